// Round 8
// baseline (330.663 us; speedup 1.0000x reference)
//
#include <hip/hip_runtime.h>
#include <cstdint>

typedef short short8 __attribute__((ext_vector_type(8)));
typedef float f32x4  __attribute__((ext_vector_type(4)));

// RNE float -> bf16 hi + bf16 lo split (scalar)
__device__ __forceinline__ void split2(float x, short& h, short& l) {
  unsigned u  = __float_as_uint(x);
  unsigned rh = u + 0x7FFFu + ((u >> 16) & 1u);
  h = (short)(rh >> 16);
  float hf = __uint_as_float((rh >> 16) << 16);
  float lf = x - hf;
  unsigned ul = __float_as_uint(lf);
  unsigned rl = ul + 0x7FFFu + ((ul >> 16) & 1u);
  l = (short)(rl >> 16);
}

// float4 -> packed bf16 hi pair + lo pair (v_cvt_pk_bf16_f32)
__device__ __forceinline__ void split4(float4 a, uint2& hp, uint2& lp) {
  unsigned hp0, hp1, lp0, lp1;
  asm("v_cvt_pk_bf16_f32 %0, %1, %2" : "=v"(hp0) : "v"(a.x), "v"(a.y));
  asm("v_cvt_pk_bf16_f32 %0, %1, %2" : "=v"(hp1) : "v"(a.z), "v"(a.w));
  float h0 = __uint_as_float(hp0 << 16);
  float h1 = __uint_as_float(hp0 & 0xFFFF0000u);
  float h2 = __uint_as_float(hp1 << 16);
  float h3 = __uint_as_float(hp1 & 0xFFFF0000u);
  float l0 = a.x - h0, l1 = a.y - h1, l2 = a.z - h2, l3 = a.w - h3;
  asm("v_cvt_pk_bf16_f32 %0, %1, %2" : "=v"(lp0) : "v"(l0), "v"(l1));
  asm("v_cvt_pk_bf16_f32 %0, %1, %2" : "=v"(lp1) : "v"(l2), "v"(l3));
  hp = make_uint2(hp0, hp1);
  lp = make_uint2(lp0, lp1);
}

// ---------------------------------------------------------------------------
__global__ __launch_bounds__(256) void init_head(int* __restrict__ head, int N)
{
  const int i = blockIdx.x * 256 + threadIdx.x;
  if (i < N) head[i] = -1;
}

// ---------------------------------------------------------------------------
// Pre-convert all weight matrices [K][64] f32 -> bf16 hi/lo in MFMA B-frag
// order. k-row segments (padded to mult of 32):
//   Wi:0(512) Wt:512(768) Wn:1280(K=16) Wc:1312(K=8) Wf:1344(256)
//   Wm1A:1600(64) Wm1B:1664(64)   total 1728 k-rows -> steps 0..53
// ---------------------------------------------------------------------------
__global__ __launch_bounds__(256) void prep_w(
    const float* __restrict__ Wi, const float* __restrict__ Wt,
    const float* __restrict__ Wn, const float* __restrict__ Wc,
    const float* __restrict__ Wf, const float* __restrict__ Wm1,
    short* __restrict__ hi, short* __restrict__ lo)
{
  int idx = blockIdx.x * 256 + threadIdx.x;
  if (idx >= 1728 * 64) return;
  int kp = idx >> 6, col = idx & 63;
  const float* W; int K, kloc, base;
  if (kp < 512)       { W = Wi;            K = 512; kloc = kp;        base = 0;    }
  else if (kp < 1280) { W = Wt;            K = 768; kloc = kp - 512;  base = 512;  }
  else if (kp < 1312) { W = Wn;            K = 16;  kloc = kp - 1280; base = 1280; }
  else if (kp < 1344) { W = Wc;            K = 8;   kloc = kp - 1312; base = 1312; }
  else if (kp < 1600) { W = Wf;            K = 256; kloc = kp - 1344; base = 1344; }
  else if (kp < 1664) { W = Wm1;           K = 64;  kloc = kp - 1600; base = 1600; }
  else                { W = Wm1 + 64 * 64; K = 64;  kloc = kp - 1664; base = 1664; }
  float x = (kloc < K) ? W[(size_t)kloc * 64 + col] : 0.f;
  short h, l; split2(x, h, l);
  int s = kloc >> 5;
  int addr = ((s * 4 + (col >> 4)) * 64 + ((col & 15) | (((kloc >> 3) & 3) << 4))) * 8 + (kloc & 7);
  size_t o = (size_t)base * 64 + addr;
  hi[o] = h; lo[o] = l;
}

// register-resident prefetch buffers (all indexing compile-time constant)
struct Wstep { uint4 h[4]; uint4 l[4]; };
struct Astep { float4 a0, a1; };

// ---------------------------------------------------------------------------
// Fused encoder v4: no LDS/barriers in K-loop + distance-2 register prefetch.
// Wave owns 16 rows; A-fragment lane l <- A[row=l&15][k=(l>>4)*8+j] loaded
// directly from global; W from L2 in prepped frag order. Double-buffered
// named register sets (Aa/Ab, Wa/Wb) keep ~20KB/wave in flight so the
// load->use chain never drains. Stage-2 via per-wave LDS patch (lgkmcnt only).
// ---------------------------------------------------------------------------
__global__ __launch_bounds__(256) void encoder(
    const float* __restrict__ image, const float* __restrict__ tweets,
    const float* __restrict__ nump, const float* __restrict__ catg,
    const short* __restrict__ Whi, const short* __restrict__ Wlo,
    const float* __restrict__ bi, const float* __restrict__ bt,
    const float* __restrict__ bn, const float* __restrict__ bc,
    const float* __restrict__ bf, float* __restrict__ nf, int M)
{
  __shared__ float hbuf[4][16 * 68 + 4];
  const int tid = threadIdx.x;
  const int m0  = blockIdx.x * 64;
  const int w   = tid >> 6, l = tid & 63;
  const int r   = l & 15;          // fragment row (within wave's 16 rows)
  const int g   = l >> 4;          // k-group: k = g*8 + j
  int grow = m0 + w * 16 + r;      // global row for A loads
  if (grow >= M) grow = M - 1;     // clamp; dup rows never stored

  f32x4 acc[4], acc2[4];
#pragma unroll
  for (int n = 0; n < 4; n++) {
    acc[n]  = (f32x4){0.f, 0.f, 0.f, 0.f};
    acc2[n] = (f32x4){0.f, 0.f, 0.f, 0.f};
  }

  auto loadW = [&](int step, Wstep& W) {
#pragma unroll
    for (int n = 0; n < 4; n++) {
      W.h[n] = *reinterpret_cast<const uint4*>(&Whi[((size_t)(step * 4 + n)) * 512 + l * 8]);
      W.l[n] = *reinterpret_cast<const uint4*>(&Wlo[((size_t)(step * 4 + n)) * 512 + l * 8]);
    }
  };
  auto loadA = [&](const float* base, int lda, int t, Astep& A) {
    const float* ap = base + (size_t)grow * lda + t * 32 + g * 8;
    A.a0 = *reinterpret_cast<const float4*>(ap);
    A.a1 = *reinterpret_cast<const float4*>(ap + 4);
  };
  auto consume = [&](const Astep& A, const Wstep& W, f32x4* ac) {
    uint2 h01, l01, h23, l23;
    split4(A.a0, h01, l01);
    split4(A.a1, h23, l23);
    uint4 ahi_u = make_uint4(h01.x, h01.y, h23.x, h23.y);
    uint4 alo_u = make_uint4(l01.x, l01.y, l23.x, l23.y);
    short8 ahi = *reinterpret_cast<short8*>(&ahi_u);
    short8 alo = *reinterpret_cast<short8*>(&alo_u);
#pragma unroll
    for (int n = 0; n < 4; n++) {
      short8 whi = *reinterpret_cast<const short8*>(&W.h[n]);
      short8 wlo = *reinterpret_cast<const short8*>(&W.l[n]);
      ac[n] = __builtin_amdgcn_mfma_f32_16x16x32_bf16(ahi, whi, ac[n], 0, 0, 0);
      ac[n] = __builtin_amdgcn_mfma_f32_16x16x32_bf16(alo, whi, ac[n], 0, 0, 0);
      ac[n] = __builtin_amdgcn_mfma_f32_16x16x32_bf16(ahi, wlo, ac[n], 0, 0, 0);
    }
  };

  // pipelined stage-1 segment: S even, W-step base B. Distance-2 prefetch.
  auto run_seg = [&](const float* base, int lda, int S, int B) {
    Astep Aa, Ab; Wstep Wa, Wb;
    loadA(base, lda, 0, Aa); loadW(B + 0, Wa);
    loadA(base, lda, 1, Ab); loadW(B + 1, Wb);
    for (int t = 0; t < S; t += 2) {
      consume(Aa, Wa, acc);
      if (t + 2 < S) { loadA(base, lda, t + 2, Aa); loadW(B + t + 2, Wa); }
      consume(Ab, Wb, acc);
      if (t + 3 < S) { loadA(base, lda, t + 3, Ab); loadW(B + t + 3, Wb); }
    }
  };

  // stage-2: per-wave D->A transpose through private LDS patch, then MFMA
  // into acc2 against Wf k-block of this segment. No cross-wave sync needed.
  auto seg2_phase = [&](int seg, const float* __restrict__ bias) {
    float* hb = hbuf[w];
#pragma unroll
    for (int n = 0; n < 4; n++) {
      const int c  = n * 16 + r;
      const float bb = bias[c];
#pragma unroll
      for (int j = 0; j < 4; j++) {
        const int row = g * 4 + j;              // D layout: row=(l>>4)*4+j
        hb[row * 68 + c] = fmaxf(acc[n][j] + bb, 0.f);
      }
      acc[n] = (f32x4){0.f, 0.f, 0.f, 0.f};
    }
    asm volatile("s_waitcnt lgkmcnt(0)" ::: "memory");
    __builtin_amdgcn_sched_barrier(0);
#pragma unroll
    for (int ks2 = 0; ks2 < 2; ks2++) {
      Astep Ah;
      Ah.a0 = *reinterpret_cast<const float4*>(&hb[r * 68 + ks2 * 32 + g * 8]);
      Ah.a1 = *reinterpret_cast<const float4*>(&hb[r * 68 + ks2 * 32 + g * 8 + 4]);
      Wstep Ws; loadW(42 + seg * 2 + ks2, Ws);
      consume(Ah, Ws, acc2);
    }
  };

  // ---- stage 1 + stage 2 per segment ----
  run_seg(image,  512, 16, 0);
  seg2_phase(0, bi);

  run_seg(tweets, 768, 24, 16);
  seg2_phase(1, bt);

  {  // num_prop (K=16: only g<2 lanes valid)
    Astep An; An.a0 = make_float4(0.f,0.f,0.f,0.f); An.a1 = An.a0;
    if (g < 2) {
      const float* ap = nump + (size_t)grow * 16 + g * 8;
      An.a0 = *reinterpret_cast<const float4*>(ap);
      An.a1 = *reinterpret_cast<const float4*>(ap + 4);
    }
    Wstep Ws; loadW(40, Ws);
    consume(An, Ws, acc);
  }
  seg2_phase(2, bn);

  {  // category (K=8: only g==0 lanes valid)
    Astep An; An.a0 = make_float4(0.f,0.f,0.f,0.f); An.a1 = An.a0;
    if (g == 0) {
      const float* ap = catg + (size_t)grow * 8;
      An.a0 = *reinterpret_cast<const float4*>(ap);
      An.a1 = *reinterpret_cast<const float4*>(ap + 4);
    }
    Wstep Ws; loadW(41, Ws);
    consume(An, Ws, acc);
  }
  seg2_phase(3, bc);

  // ---- epilogue: nf = relu(acc2 + bf) ----
  const int rb  = m0 + w * 16 + g * 4;
#pragma unroll
  for (int n = 0; n < 4; n++) {
    const int c = n * 16 + r;
    const float bb = bf[c];
#pragma unroll
    for (int j = 0; j < 4; j++) {
      const int rr = rb + j;
      if (rr < M) nf[(size_t)rr * 64 + c] = fmaxf(acc2[n][j] + bb, 0.f);
    }
  }
}

// ---------------------------------------------------------------------------
// Edge tables via MFMA. blocks [0,gT): Atab   blocks [gT,2gT): Btab
// ---------------------------------------------------------------------------
__global__ __launch_bounds__(256) void table_kernel(
    const float* __restrict__ nf, const float* __restrict__ Eet,
    const short* __restrict__ Whi, const short* __restrict__ Wlo,
    const float* __restrict__ bm1,
    float* __restrict__ Atab, float* __restrict__ Btab, int N3, int gT)
{
  const bool isB    = (int)blockIdx.x >= gT;
  const int  m0     = (isB ? (int)blockIdx.x - gT : (int)blockIdx.x) * 64;
  const int  eoff   = isB ? 64 : 0;
  const int  wstep0 = isB ? 52 : 50;
  float*     Tab    = isB ? Btab : Atab;

  __shared__ short Ahi[2][2048];
  __shared__ short Alo[2][2048];
  const int tid  = threadIdx.x;
  const int w    = tid >> 6, l = tid & 63;
  const int srow = tid >> 3;
  const int k0   = (tid & 7) * 4;
  const int i0   = k0 & 7;
  const int kg   = k0 >> 3;

#pragma unroll
  for (int ks2 = 0; ks2 < 2; ks2++) {
#pragma unroll
    for (int r2 = 0; r2 < 2; r2++) {
      const int row = srow + r2 * 32;
      const int rg  = m0 + row;
      float4 v = make_float4(0.f, 0.f, 0.f, 0.f);
      if (rg < N3) {
        const int n = rg / 3;
        const int t = rg - n * 3;
        const int k = ks2 * 32 + k0;
        float4 x = *reinterpret_cast<const float4*>(&nf[(size_t)n * 64 + k]);
        float4 e = *reinterpret_cast<const float4*>(&Eet[(size_t)t * 128 + eoff + k]);
        v.x = fmaxf(x.x + e.x, 0.f); v.y = fmaxf(x.y + e.y, 0.f);
        v.z = fmaxf(x.z + e.z, 0.f); v.w = fmaxf(x.w + e.w, 0.f);
      }
      uint2 hp, lp; split4(v, hp, lp);
      const int addr = (row >> 4) * 512 + (((row & 15) | (kg << 4)) * 8 + i0);
      *reinterpret_cast<uint2*>(&Ahi[ks2][addr]) = hp;
      *reinterpret_cast<uint2*>(&Alo[ks2][addr]) = lp;
    }
  }
  __syncthreads();

  f32x4 acc[4];
#pragma unroll
  for (int n = 0; n < 4; n++) acc[n] = (f32x4){0.f, 0.f, 0.f, 0.f};

#pragma unroll
  for (int ks2 = 0; ks2 < 2; ks2++) {
    short8 ahi = *reinterpret_cast<const short8*>(&Ahi[ks2][w * 512 + l * 8]);
    short8 alo = *reinterpret_cast<const short8*>(&Alo[ks2][w * 512 + l * 8]);
#pragma unroll
    for (int n = 0; n < 4; n++) {
      short8 whi = *reinterpret_cast<const short8*>(&Whi[((size_t)(wstep0 + ks2) * 4 + n) * 512 + l * 8]);
      short8 wlo = *reinterpret_cast<const short8*>(&Wlo[((size_t)(wstep0 + ks2) * 4 + n) * 512 + l * 8]);
      acc[n] = __builtin_amdgcn_mfma_f32_16x16x32_bf16(ahi, whi, acc[n], 0, 0, 0);
      acc[n] = __builtin_amdgcn_mfma_f32_16x16x32_bf16(alo, whi, acc[n], 0, 0, 0);
      acc[n] = __builtin_amdgcn_mfma_f32_16x16x32_bf16(ahi, wlo, acc[n], 0, 0, 0);
    }
  }

  const int rb  = m0 + w * 16 + (l >> 4) * 4;
  const int c15 = l & 15;
#pragma unroll
  for (int n = 0; n < 4; n++) {
    const int c = n * 16 + c15;
    const float bb = isB ? 0.f : bm1[c];
#pragma unroll
    for (int j = 0; j < 4; j++) {
      const int rr = rb + j;
      if (rr < N3) Tab[(size_t)rr * 64 + c] = acc[n][j] + bb;
    }
  }
}

// ---------------------------------------------------------------------------
// 16 lanes per edge: logits -> sigmoid -> Bernoulli(u) -> linked list append
// ---------------------------------------------------------------------------
__global__ __launch_bounds__(256) void edge_kernel(
    const int* __restrict__ ei, const int* __restrict__ et,
    const float* __restrict__ u,
    const float* __restrict__ Atab, const float* __restrict__ Btab,
    const float* __restrict__ Wm2, const float* __restrict__ bm2,
    int* __restrict__ head, int* __restrict__ nxt, int E)
{
  const int tid = threadIdx.x;
  const int e   = blockIdx.x * 16 + (tid >> 4);
  const int sub = tid & 15;
  if (e >= E) return;

  const int sn = ei[e];
  const int dn = ei[E + e];
  const int t  = et[e];

  float4 a  = *reinterpret_cast<const float4*>(Atab + ((size_t)sn * 3 + t) * 64 + sub * 4);
  float4 b  = *reinterpret_cast<const float4*>(Btab + ((size_t)dn * 3 + t) * 64 + sub * 4);
  float4 wv = *reinterpret_cast<const float4*>(Wm2 + sub * 4);

  float v = fmaxf(a.x + b.x, 0.f) * wv.x;
  v = fmaf(fmaxf(a.y + b.y, 0.f), wv.y, v);
  v = fmaf(fmaxf(a.z + b.z, 0.f), wv.z, v);
  v = fmaf(fmaxf(a.w + b.w, 0.f), wv.w, v);
  v += __shfl_xor(v, 1);
  v += __shfl_xor(v, 2);
  v += __shfl_xor(v, 4);
  v += __shfl_xor(v, 8);

  if (sub == 0) {
    const float p = 1.f / (1.f + expf(-(v + bm2[0])));
    if (u[e] < p) {
      nxt[e] = atomicExch(&head[sn], e);
    }
  }
}

// ---------------------------------------------------------------------------
// one wave per node: walk chain, accumulate nf[dst] in double, out = agg@Wcls
// ---------------------------------------------------------------------------
__global__ __launch_bounds__(256) void node_kernel(
    const int* __restrict__ head, const int* __restrict__ nxt,
    const int* __restrict__ ei,
    const float* __restrict__ nf,
    const float* __restrict__ Wcls, const float* __restrict__ bcls,
    float* __restrict__ out, int N, int E)
{
  const int n    = (int)((blockIdx.x * (unsigned)blockDim.x + threadIdx.x) >> 6);
  const int lane = threadIdx.x & 63;
  if (n >= N) return;

  double acc = 0.0;
  int    c   = 0;
  int    e   = head[n];
  while (e >= 0) {
    const int dn = ei[E + e];
    acc += (double)nf[(size_t)dn * 64 + lane];
    c++;
    e = nxt[e];
  }

  const float agg = (c > 0) ? (float)(acc / (double)c) : nf[(size_t)n * 64 + lane];
  float r0 = agg * Wcls[lane * 2 + 0];
  float r1 = agg * Wcls[lane * 2 + 1];
#pragma unroll
  for (int off = 32; off; off >>= 1) {
    r0 += __shfl_xor(r0, off, 64);
    r1 += __shfl_xor(r1, off, 64);
  }
  if (lane == 0) {
    out[(size_t)n * 2 + 0] = r0 + bcls[0];
    out[(size_t)n * 2 + 1] = r1 + bcls[1];
  }
}

// ---------------------------------------------------------------------------
extern "C" void kernel_launch(void* const* d_in, const int* in_sizes, int n_in,
                              void* d_out, int out_size, void* d_ws, size_t ws_size,
                              hipStream_t stream)
{
  const float* image    = (const float*)d_in[0];
  const float* tweets   = (const float*)d_in[1];
  const float* num_prop = (const float*)d_in[2];
  const float* category = (const float*)d_in[3];
  const int*   ei       = (const int*)  d_in[4];
  const int*   et       = (const int*)  d_in[5];
  // d_in[6] = eps : unused (z is dead code)
  const float* u        = (const float*)d_in[7];
  const float* Wi  = (const float*)d_in[8],  *bi  = (const float*)d_in[9];
  const float* Wt  = (const float*)d_in[10], *bt  = (const float*)d_in[11];
  const float* Wn  = (const float*)d_in[12], *bn  = (const float*)d_in[13];
  const float* Wc  = (const float*)d_in[14], *bc  = (const float*)d_in[15];
  const float* Wf  = (const float*)d_in[16], *bf  = (const float*)d_in[17];
  const float* Eet = (const float*)d_in[18];
  // d_in[19..22] = Wmu,bmu,Wlv,blv : unused (z is dead code)
  const float* Wm1 = (const float*)d_in[23], *bm1 = (const float*)d_in[24];
  const float* Wm2 = (const float*)d_in[25], *bm2 = (const float*)d_in[26];
  const float* Wcls= (const float*)d_in[27], *bcls= (const float*)d_in[28];
  float* out = (float*)d_out;

  const int N = in_sizes[0] / 512;
  const int E = in_sizes[5];

  float* ws = (float*)d_ws;
  size_t off = 0;
  float* nf     = ws + off;  off += (size_t)N * 64;
  float* Atab   = ws + off;  off += (size_t)N * 3 * 64;
  float* Btab   = ws + off;  off += (size_t)N * 3 * 64;
  int*   head   = (int*)(ws + off);  off += (size_t)N;
  int*   nxt    = (int*)(ws + off);  off += (size_t)E;
  short* Wfhi   = (short*)(ws + off);  off += (1728 * 64) / 2;
  short* Wflo   = (short*)(ws + off);  off += (1728 * 64) / 2;

  init_head<<<(N + 255) / 256, 256, 0, stream>>>(head, N);

  prep_w<<<(1728 * 64 + 255) / 256, 256, 0, stream>>>(Wi, Wt, Wn, Wc, Wf, Wm1,
                                                      Wfhi, Wflo);

  const int gN = (N + 63) / 64;
  encoder<<<gN, 256, 0, stream>>>(image, tweets, num_prop, category,
                                  Wfhi, Wflo, bi, bt, bn, bc, bf, nf, N);

  const int N3 = N * 3;
  const int gT = (N3 + 63) / 64;
  table_kernel<<<2 * gT, 256, 0, stream>>>(nf, Eet, Wfhi, Wflo, bm1,
                                           Atab, Btab, N3, gT);

  edge_kernel<<<(E + 15) / 16, 256, 0, stream>>>(ei, et, u, Atab, Btab,
                                                 Wm2, bm2, head, nxt, E);

  node_kernel<<<(N + 3) / 4, 256, 0, stream>>>(head, nxt, ei, nf, Wcls, bcls,
                                               out, N, E);
}